// Round 2
// baseline (2292.056 us; speedup 1.0000x reference)
//
#include <hip/hip_runtime.h>

typedef _Float16 f16;
typedef _Float16 h2 __attribute__((ext_vector_type(2)));
typedef _Float16 h8 __attribute__((ext_vector_type(8)));
typedef float    f4 __attribute__((ext_vector_type(4)));

#define S_  256
#define B_  1024
#define D_  64
#define H_  128
#define Z_  32
#define BD_ (B_*D_)
#define NSTEP 514

__device__ __forceinline__ float fdot2(h2 a, h2 b, float c) {
#if __has_builtin(__builtin_amdgcn_fdot2)
  return __builtin_amdgcn_fdot2(a, b, c, false);
#else
  return c + (float)a[0]*(float)b[0] + (float)a[1]*(float)b[1];
#endif
}

__device__ __forceinline__ float dot8(h8 a, h8 w, float acc) {
  h2 a0 = __builtin_shufflevector(a, a, 0, 1), w0 = __builtin_shufflevector(w, w, 0, 1);
  h2 a1 = __builtin_shufflevector(a, a, 2, 3), w1 = __builtin_shufflevector(w, w, 2, 3);
  h2 a2 = __builtin_shufflevector(a, a, 4, 5), w2 = __builtin_shufflevector(w, w, 4, 5);
  h2 a3 = __builtin_shufflevector(a, a, 6, 7), w3 = __builtin_shufflevector(w, w, 6, 7);
  acc = fdot2(a0, w0, acc);
  acc = fdot2(a1, w1, acc);
  acc = fdot2(a2, w2, acc);
  acc = fdot2(a3, w3, acc);
  return acc;
}

__device__ __forceinline__ h8 ld8(const float* p) {   // 32B-aligned src
  f4 a = *(const f4*)p;
  f4 b = *(const f4*)(p + 4);
  h8 w;
  w[0]=(f16)a[0]; w[1]=(f16)a[1]; w[2]=(f16)a[2]; w[3]=(f16)a[3];
  w[4]=(f16)b[0]; w[5]=(f16)b[1]; w[6]=(f16)b[2]; w[7]=(f16)b[3];
  return w;
}

__device__ __forceinline__ float sigm(float x) { return 1.f / (1.f + __expf(-x)); }
__device__ __forceinline__ float tanh_(float x) {
  float e = __expf(-2.f * fabsf(x));
  float t = (1.f - e) / (1.f + e);
  return copysignf(t, x);
}

// chunk->slot transpose: lanes differing in kq (k-quarter) read consecutive
// 16B slots -> banks {0,8,16,24}+off instead of 4-way aliasing on bank 0/16.
__device__ __forceinline__ int ahslot(int ch) { return ((ch & 3) << 2) | (ch >> 2); } // 16 chunks
__device__ __forceinline__ int xvslot(int ch) { return ((ch & 1) << 2) | (ch >> 1); } // 8 chunks

// ---------------------------------------------------------------------------
// GRU: 512 blocks x 2 batch rows, 512 threads, 4-way k-split (t = 4*jh + kq).
// Round-2: transposed actH/xv slots (kills 4-way ds_read_b128 bank conflicts),
// xs prefetched a FULL iteration ahead (L3/HBM latency never hits the barrier).
// ---------------------------------------------------------------------------
__global__ __launch_bounds__(512, 4) void gru_kernel(
    const float* __restrict__ xs, const float* __restrict__ Wih,
    const float* __restrict__ Whh, const float* __restrict__ bih,
    const float* __restrict__ bhh, float* __restrict__ hT)
{
  __shared__ h8 actH[2][16][2];            // [buf][slot][b]
  __shared__ h8 xv[2][8][2];               // [buf][slot][b]

  const int t  = threadIdx.x;
  const int b0 = blockIdx.x * 2;
  const int jh = t >> 2;                   // 0..127 output row
  const int kq = t & 3;                    // k quarter (Whh 32 elems, Wih 16)

  h8 whr[4], whz[4], whn[4], wxr[2], wxz[2], wxn[2];
  {
    const float* pr = Whh + jh*H_        + kq*32;
    const float* pz = Whh + (jh+128)*H_  + kq*32;
    const float* pn = Whh + (jh+256)*H_  + kq*32;
    #pragma unroll
    for (int c = 0; c < 4; ++c) {
      whr[c] = ld8(pr + c*8);
      whz[c] = ld8(pz + c*8);
      whn[c] = ld8(pn + c*8);
    }
    const float* qr = Wih + jh*D_        + kq*16;
    const float* qz = Wih + (jh+128)*D_  + kq*16;
    const float* qn = Wih + (jh+256)*D_  + kq*16;
    #pragma unroll
    for (int c = 0; c < 2; ++c) {
      wxr[c] = ld8(qr + c*8);
      wxz[c] = ld8(qz + c*8);
      wxn[c] = ld8(qn + c*8);
    }
  }
  const float bir = bih[jh], biz = bih[jh+128], bin = bih[jh+256];
  const float bhr = bhh[jh], bhz = bhh[jh+128], bhn = bhh[jh+256];
  float h0m = 0.f, h1m = 0.f;              // fp32 h master at kq==0 lanes

  if (t < 32) { h8 zz = {}; actH[0][t>>1][t&1] = zz; }
  if (t < 128) {                            // x for step 0 (s = S_-1 input)
    int b = t >> 6, d = t & 63;
    float x0 = xs[(S_-1)*BD_ + (b0+b)*D_ + d];
    ((f16*)xv[0])[(xvslot(d>>3)*2 + b)*8 + (d&7)] = (f16)x0;
  }
  float xcur = 0.f;                         // x for step 1, written at s=0
  if (t < 128) {
    int b = t >> 6, d = t & 63;
    xcur = xs[(S_-2)*BD_ + (b0+b)*D_ + d];
  }
  __syncthreads();

  int p = 0;
  #pragma unroll 1
  for (int s = 0; s < S_; ++s) {
    float xnew = 0.f;                       // prefetch a FULL iteration ahead
    if (s < S_-2 && t < 128) {
      int b = t >> 6, d = t & 63;
      xnew = xs[(S_-3-s)*BD_ + (b0+b)*D_ + d];
    }
    // quarter-k partial dots, 8 independent chains (transposed slots: c*4+kq)
    float pr0=0.f, pz0=0.f, pnh0=0.f, pnx0=0.f;
    float pr1=0.f, pz1=0.f, pnh1=0.f, pnx1=0.f;
    #pragma unroll
    for (int c = 0; c < 4; ++c) {
      h8 a0 = actH[p][(c<<2) | kq][0];
      h8 a1 = actH[p][(c<<2) | kq][1];
      pr0  = dot8(a0, whr[c], pr0);   pr1  = dot8(a1, whr[c], pr1);
      pz0  = dot8(a0, whz[c], pz0);   pz1  = dot8(a1, whz[c], pz1);
      pnh0 = dot8(a0, whn[c], pnh0);  pnh1 = dot8(a1, whn[c], pnh1);
    }
    #pragma unroll
    for (int c = 0; c < 2; ++c) {
      h8 a0 = xv[p][(c<<2) | kq][0];
      h8 a1 = xv[p][(c<<2) | kq][1];
      pr0  = dot8(a0, wxr[c], pr0);   pr1  = dot8(a1, wxr[c], pr1);
      pz0  = dot8(a0, wxz[c], pz0);   pz1  = dot8(a1, wxz[c], pz1);
      pnx0 = dot8(a0, wxn[c], pnx0);  pnx1 = dot8(a1, wxn[c], pnx1);
    }
    // butterfly over kq (lanes 4j..4j+3, same wave)
    pr0  += __shfl_xor(pr0, 1, 64);  pr0  += __shfl_xor(pr0, 2, 64);
    pz0  += __shfl_xor(pz0, 1, 64);  pz0  += __shfl_xor(pz0, 2, 64);
    pnh0 += __shfl_xor(pnh0, 1, 64); pnh0 += __shfl_xor(pnh0, 2, 64);
    pnx0 += __shfl_xor(pnx0, 1, 64); pnx0 += __shfl_xor(pnx0, 2, 64);
    pr1  += __shfl_xor(pr1, 1, 64);  pr1  += __shfl_xor(pr1, 2, 64);
    pz1  += __shfl_xor(pz1, 1, 64);  pz1  += __shfl_xor(pz1, 2, 64);
    pnh1 += __shfl_xor(pnh1, 1, 64); pnh1 += __shfl_xor(pnh1, 2, 64);
    pnx1 += __shfl_xor(pnx1, 1, 64); pnx1 += __shfl_xor(pnx1, 2, 64);

    if (kq == 0) {
      float r0  = sigm(pr0 + bir + bhr);
      float zg0 = sigm(pz0 + biz + bhz);
      float n0  = tanh_(pnx0 + bin + r0*(pnh0 + bhn));
      h0m = (1.f - zg0)*n0 + zg0*h0m;
      float r1  = sigm(pr1 + bir + bhr);
      float zg1 = sigm(pz1 + biz + bhz);
      float n1  = tanh_(pnx1 + bin + r1*(pnh1 + bhn));
      h1m = (1.f - zg1)*n1 + zg1*h1m;
      const int sl = ahslot(jh >> 3);
      ((f16*)actH[p^1])[(sl*2 + 0)*8 + (jh&7)] = (f16)h0m;
      ((f16*)actH[p^1])[(sl*2 + 1)*8 + (jh&7)] = (f16)h1m;
    }
    if (s < S_-1 && t < 128) {
      int b = t >> 6, d = t & 63;
      ((f16*)xv[p^1])[(xvslot(d>>3)*2 + b)*8 + (d&7)] = (f16)xcur;
    }
    xcur = xnew;
    __syncthreads();
    p ^= 1;
  }
  if (kq == 0) {
    hT[(b0+0)*H_ + jh] = h0m;
    hT[(b0+1)*H_ + jh] = h1m;
  }
}

// ---------------------------------------------------------------------------
// Encoder head (unchanged; tiny): 256 blocks x 4 rows.
// ---------------------------------------------------------------------------
__global__ __launch_bounds__(256) void enc_kernel(
    const float* __restrict__ hT, const float* __restrict__ encW,
    const float* __restrict__ encB, const float* __restrict__ qW,
    const float* __restrict__ qB, const float* __restrict__ eps,
    const float* __restrict__ pm, const float* __restrict__ pls,
    float* __restrict__ z0, float* __restrict__ out)
{
  __shared__ float hTl[4][128];
  __shared__ float ctx[4][64];
  __shared__ float ql[4][64];
  const int t = threadIdx.x;
  const int b0 = blockIdx.x * 4;
  const int lb = t >> 6, j = t & 63;

  for (int i = t; i < 512; i += 256) hTl[i>>7][i&127] = hT[b0*H_ + i];
  __syncthreads();

  float acc = encB[j];
  #pragma unroll
  for (int k = 0; k < 128; k += 4) {
    f4 w = *(const f4*)&encW[j*128 + k];
    acc += hTl[lb][k]*w[0] + hTl[lb][k+1]*w[1] + hTl[lb][k+2]*w[2] + hTl[lb][k+3]*w[3];
  }
  ctx[lb][j] = acc;
  __syncthreads();

  float q = qB[j];
  #pragma unroll
  for (int k = 0; k < 64; k += 4) {
    f4 w = *(const f4*)&qW[j*64 + k];
    q += ctx[lb][k]*w[0] + ctx[lb][k+1]*w[1] + ctx[lb][k+2]*w[2] + ctx[lb][k+3]*w[3];
  }
  ql[lb][j] = q;
  __syncthreads();

  float kl = 0.f;
  if (j < 32) {
    float mean = ql[lb][j], ls = ql[lb][j+32];
    z0[(b0+lb)*Z_ + j] = mean + __expf(ls)*eps[(b0+lb)*Z_ + j];
    float pmj = pm[j], plsj = pls[j];
    float dm = mean - pmj;
    kl = plsj - ls + (__expf(2.f*ls) + dm*dm) / (2.f*__expf(2.f*plsj)) - 0.5f;
  }
  #pragma unroll
  for (int s2 = 32; s2 > 0; s2 >>= 1) kl += __shfl_down(kl, s2, 64);
  if (j == 0) atomicAdd(out + 1, kl * (1.f/1024.f));
}

// ---------------------------------------------------------------------------
// SDE: 1024 blocks x 1 batch row, 256 threads.
// Round-2: (a) gh/h2 chunk slots transposed -> phase-3 ds_read_b128 hits 4
// distinct banks (was 4-way conflict = 3.4e7 cycles/dispatch); (b) phase-1
// W1 and proj pW moved to LDS (transposed, lane-indexed b128 reads) ->
// ~32 fewer unified regs -> launch_bounds(256,5) = 5 blocks/CU (was 4).
// ---------------------------------------------------------------------------
__global__ __launch_bounds__(256, 5) void sde_kernel(
    const float* __restrict__ z0, const float* __restrict__ ts,
    const float* __restrict__ dW, const float* __restrict__ xs,
    const float* __restrict__ fW1, const float* __restrict__ fb1,
    const float* __restrict__ fW2, const float* __restrict__ fb2,
    const float* __restrict__ fW3, const float* __restrict__ fb3,
    const float* __restrict__ gW1, const float* __restrict__ gb1,
    const float* __restrict__ gW2, const float* __restrict__ gb2,
    const float* __restrict__ pW, const float* __restrict__ pb,
    float* __restrict__ out)
{
  __shared__ h8 hAct[48];        // slots: 0..15 h1 (linear), 16..31 gh (T), 32..47 h2 (T)
  __shared__ h8 zc[4];           // z f16 (32 values)
  __shared__ h8 w1T[4*256];      // [kchunk][row] W1 rows of [fW1;gW1] (z-part)
  __shared__ h8 pwT[4*64];       // [kchunk][row] proj rows
  __shared__ float tsL[516];

  const int t = threadIdx.x;
  const int b = blockIdx.x;

  // --- phase-1 role: row t of [fW1; gW1]; z-weights go to LDS (transposed) ---
  const int row = t;
  const float* w1src = (row < 128) ? (fW1 + row*33) : (gW1 + (row-128)*33);
  const float twv = w1src[0];
  const float b1v = (row < 128) ? fb1[row] : gb1[row-128];
  #pragma unroll
  for (int c = 0; c < 4; ++c) {       // stride-33 rows: scalar loads (startup only)
    h8 w;
    #pragma unroll
    for (int e = 0; e < 8; ++e) w[e] = (f16)w1src[1 + c*8 + e];
    w1T[c*256 + row] = w;
  }
  // --- phase-2 role: out j2 = t>>1, k-half kh = t&1 ---
  const int j2 = t >> 1, kh = t & 1;
  const float b2v = fb2[j2];
  h8 w2[8];
  {
    const float* p2 = fW2 + j2*H_ + kh*64;
    #pragma unroll
    for (int c = 0; c < 8; ++c) w2[c] = ld8(p2 + c*8);
  }
  // --- phase-3 role: zi = t>>3, sel (0 drift / 1 diff) = (t>>2)&1, kq = t&3 ---
  const int zi = t >> 3, sel = (t >> 2) & 1, kq = t & 3;
  h8 w3[4];
  {
    const float* p3 = sel ? (gW2 + zi*H_ + kq*32) : (fW3 + zi*H_ + kq*32);
    #pragma unroll
    for (int c = 0; c < 4; ++c) w3[c] = ld8(p3 + c*8);
  }
  const float b3v = sel ? gb2[zi] : fb3[zi];
  const bool zmaster = ((t & 7) == 0);
  // --- proj role: d = t (t<64); weights go to LDS (transposed) ---
  float pbv = 0.f;
  if (t < 64) {
    const float* pp = pW + t*Z_;
    #pragma unroll
    for (int c = 0; c < 4; ++c) pwT[c*64 + t] = ld8(pp + c*8);
    pbv = pb[t];
  }

  for (int i = t; i < 515; i += 256) tsL[i] = ts[i];
  float zm = 0.f;                     // fp32 z master at (t&7)==0 lanes
  if (zmaster) {
    zm = z0[b*Z_ + zi];
    ((f16*)zc)[zi] = (f16)zm;
  }
  float loss = 0.f;
  __syncthreads();

  #pragma unroll 1
  for (int l = 0; l < NSTEP; ++l) {
    const float tl  = tsL[l];
    const float dt  = tsL[l+1] - tl;
    const float sdt = sqrtf(dt);
    const int ln = l + 1;
    const bool ev = ((ln & 1) == 0) && ln >= 2 && ln <= 512;
    const bool od = ((ln & 1) == 1) && ln >= 3 && ln <= 511;
    float dwv = 0.f;
    if (zmaster) dwv = dW[(l*B_ + b)*Z_ + zi];
    float xsv = 0.f;
    if (ev && t < 64) xsv = xs[(((ln-2)>>1)*B_ + b)*D_ + t];

    // phase 1: h1/gh = relu([t,z] @ W1.T + b), one row per thread, W1 from LDS
    {
      h8 wv0 = w1T[0*256 + row];
      h8 wv1 = w1T[1*256 + row];
      h8 wv2 = w1T[2*256 + row];
      h8 wv3 = w1T[3*256 + row];
      float a = fmaf(twv, tl, b1v);
      a = dot8(zc[0], wv0, a);
      a = dot8(zc[1], wv1, a);
      a = dot8(zc[2], wv2, a);
      a = dot8(zc[3], wv3, a);
      a = fmaxf(a, 0.f);
      const int sl = (row < 128) ? (row >> 3)
                                 : (16 + ahslot((row - 128) >> 3));
      ((f16*)hAct)[sl*8 + (row & 7)] = (f16)a;
    }
    __syncthreads();   // A

    // phase 2: h2 = relu(h1 @ W2.T + b2), half-k + pair shfl (h1 slots linear)
    {
      const int base = kh * 8;
      float c0 = 0.f, c1 = 0.f, c2 = 0.f, c3 = 0.f;
      c0 = dot8(hAct[base+0], w2[0], c0);
      c1 = dot8(hAct[base+1], w2[1], c1);
      c2 = dot8(hAct[base+2], w2[2], c2);
      c3 = dot8(hAct[base+3], w2[3], c3);
      c0 = dot8(hAct[base+4], w2[4], c0);
      c1 = dot8(hAct[base+5], w2[5], c1);
      c2 = dot8(hAct[base+6], w2[6], c2);
      c3 = dot8(hAct[base+7], w2[7], c3);
      float pp = (c0 + c1) + (c2 + c3);
      pp += __shfl_xor(pp, 1, 64);
      if (kh == 0) {
        float acc = fmaxf(pp + b2v, 0.f);
        ((f16*)hAct)[(32 + ahslot(j2 >> 3))*8 + (j2&7)] = (f16)acc;
      }
    }
    __syncthreads();   // B

    // phase 3: drift/diff quarter-k dots on TRANSPOSED slots (region + c*4 + kq):
    // lanes differing in kq hit 4 distinct banks -> conflict-free.
    {
      const int rg = sel ? 16 : 32;            // diff reads gh, drift reads h2
      float c0 = 0.f, c1 = 0.f;
      c0 = dot8(hAct[rg +  0 + kq], w3[0], c0);
      c1 = dot8(hAct[rg +  4 + kq], w3[1], c1);
      c0 = dot8(hAct[rg +  8 + kq], w3[2], c0);
      c1 = dot8(hAct[rg + 12 + kq], w3[3], c1);
      float pp = c0 + c1;
      pp += __shfl_xor(pp, 1, 64);
      pp += __shfl_xor(pp, 2, 64);
      float acc = pp + b3v;                    // all 4 lanes of quartet agree
      float other = __shfl_xor(acc, 4, 64);    // drift lanes get diff, vice versa
      if (zmaster) {                           // sel==0 here: acc=drift, other=diff
        zm += acc*dt + other*(sdt*dwv);
        ((f16*)zc)[zi] = (f16)zm;
      }
    }
    __syncthreads();   // C

    // fused projection (wave 0) on needed steps, pW from LDS
    if ((ev || od) && t < 64) {
      h8 pw0 = pwT[0*64 + t];
      h8 pw1 = pwT[1*64 + t];
      h8 pw2 = pwT[2*64 + t];
      h8 pw3 = pwT[3*64 + t];
      float c0 = 0.f, c1 = 0.f;
      c0 = dot8(zc[0], pw0, c0);
      c1 = dot8(zc[1], pw1, c1);
      c0 = dot8(zc[2], pw2, c0);
      c1 = dot8(zc[3], pw3, c1);
      float acc = pbv + c0 + c1;
      if (ev) { float d2 = acc - xsv; loss = fmaf(d2, d2, loss); }
      else out[2 + (((ln-3)>>1)*B_ + b)*D_ + t] = acc;
    }
  }

  if (t < 64) {
    #pragma unroll
    for (int s2 = 32; s2 > 0; s2 >>= 1) loss += __shfl_down(loss, s2, 64);
    if (t == 0) atomicAdd(out + 0, loss * (1.f/16777216.f));
  }
}

extern "C" void kernel_launch(void* const* d_in, const int* in_sizes, int n_in,
                              void* d_out, int out_size, void* d_ws, size_t ws_size,
                              hipStream_t stream) {
  (void)in_sizes; (void)n_in; (void)out_size; (void)ws_size;
  const float* xs   = (const float*)d_in[0];
  const float* ts   = (const float*)d_in[1];
  const float* eps  = (const float*)d_in[2];
  const float* dWp  = (const float*)d_in[3];
  const float* Wih  = (const float*)d_in[4];
  const float* Whh  = (const float*)d_in[5];
  const float* bih  = (const float*)d_in[6];
  const float* bhh  = (const float*)d_in[7];
  const float* encW = (const float*)d_in[8];
  const float* encB = (const float*)d_in[9];
  const float* qW   = (const float*)d_in[10];
  const float* qB   = (const float*)d_in[11];
  const float* fW1  = (const float*)d_in[12];
  const float* fb1  = (const float*)d_in[13];
  const float* fW2  = (const float*)d_in[14];
  const float* fb2  = (const float*)d_in[15];
  const float* fW3  = (const float*)d_in[16];
  const float* fb3  = (const float*)d_in[17];
  const float* gW1  = (const float*)d_in[18];
  const float* gb1  = (const float*)d_in[19];
  const float* gW2  = (const float*)d_in[20];
  const float* gb2  = (const float*)d_in[21];
  const float* pW   = (const float*)d_in[22];
  const float* pb   = (const float*)d_in[23];
  const float* pm   = (const float*)d_in[24];
  const float* pls  = (const float*)d_in[25];

  float* out = (float*)d_out;
  float* ws  = (float*)d_ws;
  float* hT = ws;              // 1024*128 floats
  float* z0 = ws + 131072;     // 1024*32 floats

  hipMemsetAsync(d_out, 0, 2*sizeof(float), stream);
  hipLaunchKernelGGL(gru_kernel, dim3(512), dim3(512), 0, stream,
                     xs, Wih, Whh, bih, bhh, hT);
  hipLaunchKernelGGL(enc_kernel, dim3(256), dim3(256), 0, stream,
                     hT, encW, encB, qW, qB, eps, pm, pls, z0, out);
  hipLaunchKernelGGL(sde_kernel, dim3(1024), dim3(256), 0, stream,
                     z0, ts, dWp, xs, fW1, fb1, fW2, fb2, fW3, fb3,
                     gW1, gb1, gW2, gb2, pW, pb, out);
}

// Round 3
// 1421.428 us; speedup vs baseline: 1.6125x; 1.6125x over previous
//
#include <hip/hip_runtime.h>

typedef _Float16 f16;
typedef _Float16 h2 __attribute__((ext_vector_type(2)));
typedef _Float16 h8 __attribute__((ext_vector_type(8)));
typedef float    f4 __attribute__((ext_vector_type(4)));

#define S_  256
#define B_  1024
#define D_  64
#define H_  128
#define Z_  32
#define BD_ (B_*D_)
#define NSTEP 514

__device__ __forceinline__ float fdot2(h2 a, h2 b, float c) {
#if __has_builtin(__builtin_amdgcn_fdot2)
  return __builtin_amdgcn_fdot2(a, b, c, false);
#else
  return c + (float)a[0]*(float)b[0] + (float)a[1]*(float)b[1];
#endif
}

__device__ __forceinline__ float dot8(h8 a, h8 w, float acc) {
  h2 a0 = __builtin_shufflevector(a, a, 0, 1), w0 = __builtin_shufflevector(w, w, 0, 1);
  h2 a1 = __builtin_shufflevector(a, a, 2, 3), w1 = __builtin_shufflevector(w, w, 2, 3);
  h2 a2 = __builtin_shufflevector(a, a, 4, 5), w2 = __builtin_shufflevector(w, w, 4, 5);
  h2 a3 = __builtin_shufflevector(a, a, 6, 7), w3 = __builtin_shufflevector(w, w, 6, 7);
  acc = fdot2(a0, w0, acc);
  acc = fdot2(a1, w1, acc);
  acc = fdot2(a2, w2, acc);
  acc = fdot2(a3, w3, acc);
  return acc;
}

__device__ __forceinline__ h8 ld8(const float* p) {   // 32B-aligned src
  f4 a = *(const f4*)p;
  f4 b = *(const f4*)(p + 4);
  h8 w;
  w[0]=(f16)a[0]; w[1]=(f16)a[1]; w[2]=(f16)a[2]; w[3]=(f16)a[3];
  w[4]=(f16)b[0]; w[5]=(f16)b[1]; w[6]=(f16)b[2]; w[7]=(f16)b[3];
  return w;
}

__device__ __forceinline__ float sigm(float x) { return 1.f / (1.f + __expf(-x)); }
__device__ __forceinline__ float tanh_(float x) {
  float e = __expf(-2.f * fabsf(x));
  float t = (1.f - e) / (1.f + e);
  return copysignf(t, x);
}

// ---------------------------------------------------------------------------
// GRU: round-0 structure (best measured: ~628us). 512 blocks x 2 batch rows,
// 256 threads, k-half split across bit 7 (kh wave-uniform -> every actH/xv
// read is a broadcast, conflict-free), part[] LDS exchange, 2 barriers/step.
// ---------------------------------------------------------------------------
__global__ __launch_bounds__(256, 2) void gru_kernel(
    const float* __restrict__ xs, const float* __restrict__ Wih,
    const float* __restrict__ Whh, const float* __restrict__ bih,
    const float* __restrict__ bhh, float* __restrict__ hT)
{
  __shared__ h8 actH[16][2];               // h f16 [chunk][b]
  __shared__ h8 xv[8][2];                  // x f16 [chunk][b]
  __shared__ float part[2][2][4][128];     // [kh][b][r,z,nh,nx][jh]

  const int t  = threadIdx.x;
  const int b0 = blockIdx.x * 2;
  const int jh = t & 127;
  const int kh = t >> 7;

  h8 whr[8], whz[8], whn[8], wxr[4], wxz[4], wxn[4];
  {
    const float* pr = Whh + jh*H_        + kh*64;
    const float* pz = Whh + (jh+128)*H_  + kh*64;
    const float* pn = Whh + (jh+256)*H_  + kh*64;
    #pragma unroll
    for (int c = 0; c < 8; ++c) {
      whr[c] = ld8(pr + c*8);
      whz[c] = ld8(pz + c*8);
      whn[c] = ld8(pn + c*8);
    }
    const float* qr = Wih + jh*D_        + kh*32;
    const float* qz = Wih + (jh+128)*D_  + kh*32;
    const float* qn = Wih + (jh+256)*D_  + kh*32;
    #pragma unroll
    for (int c = 0; c < 4; ++c) {
      wxr[c] = ld8(qr + c*8);
      wxz[c] = ld8(qz + c*8);
      wxn[c] = ld8(qn + c*8);
    }
  }
  const int gb = t >> 7, hd = t & 127;     // gate-phase role
  const float bir = bih[hd], biz = bih[hd+128], bin = bih[hd+256];
  const float bhr = bhh[hd], bhz = bhh[hd+128], bhn = bhh[hd+256];
  float hmast = 0.f;

  if (t < 32) { h8 zz = {}; actH[t>>1][t&1] = zz; }
  if (t < 128) {
    int b = t >> 6, d = t & 63;
    float x0 = xs[(S_-1)*BD_ + (b0+b)*D_ + d];
    ((f16*)xv)[((d>>3)*2 + b)*8 + (d&7)] = (f16)x0;
  }
  __syncthreads();

  #pragma unroll 1
  for (int s = 0; s < S_; ++s) {
    float xnext = 0.f;
    if (s < S_-1 && t < 128) {
      int b = t >> 6, d = t & 63;
      xnext = xs[(S_-2-s)*BD_ + (b0+b)*D_ + d];
    }
    // partial dots, 8 independent chains (2 batches x {r,z,nh,(nx)})
    float pr0=0.f, pz0=0.f, pnh0=0.f, pnx0=0.f;
    float pr1=0.f, pz1=0.f, pnh1=0.f, pnx1=0.f;
    #pragma unroll
    for (int c = 0; c < 8; ++c) {
      h8 a0 = actH[kh*8 + c][0];
      h8 a1 = actH[kh*8 + c][1];
      pr0  = dot8(a0, whr[c], pr0);   pr1  = dot8(a1, whr[c], pr1);
      pz0  = dot8(a0, whz[c], pz0);   pz1  = dot8(a1, whz[c], pz1);
      pnh0 = dot8(a0, whn[c], pnh0);  pnh1 = dot8(a1, whn[c], pnh1);
    }
    #pragma unroll
    for (int c = 0; c < 4; ++c) {
      h8 a0 = xv[kh*4 + c][0];
      h8 a1 = xv[kh*4 + c][1];
      pr0  = dot8(a0, wxr[c], pr0);   pr1  = dot8(a1, wxr[c], pr1);
      pz0  = dot8(a0, wxz[c], pz0);   pz1  = dot8(a1, wxz[c], pz1);
      pnx0 = dot8(a0, wxn[c], pnx0);  pnx1 = dot8(a1, wxn[c], pnx1);
    }
    part[kh][0][0][jh] = pr0;   part[kh][1][0][jh] = pr1;
    part[kh][0][1][jh] = pz0;   part[kh][1][1][jh] = pz1;
    part[kh][0][2][jh] = pnh0;  part[kh][1][2][jh] = pnh1;
    part[kh][0][3][jh] = pnx0;  part[kh][1][3][jh] = pnx1;
    __syncthreads();

    // gate math: thread (gb, hd) owns h[gb][hd] master fp32
    {
      float pr  = part[0][gb][0][hd] + part[1][gb][0][hd];
      float pz  = part[0][gb][1][hd] + part[1][gb][1][hd];
      float pnh = part[0][gb][2][hd] + part[1][gb][2][hd];
      float pnx = part[0][gb][3][hd] + part[1][gb][3][hd];
      float r  = sigm(pr + bir + bhr);
      float zg = sigm(pz + biz + bhz);
      float n  = tanh_(pnx + bin + r*(pnh + bhn));
      hmast = (1.f - zg)*n + zg*hmast;
      ((f16*)actH)[((hd>>3)*2 + gb)*8 + (hd&7)] = (f16)hmast;
    }
    if (s < S_-1 && t < 128) {
      int b = t >> 6, d = t & 63;
      ((f16*)xv)[((d>>3)*2 + b)*8 + (d&7)] = (f16)xnext;
    }
    __syncthreads();
  }
  hT[(b0 + gb)*H_ + hd] = hmast;
}

// ---------------------------------------------------------------------------
// Encoder head (unchanged; tiny): 256 blocks x 4 rows.
// ---------------------------------------------------------------------------
__global__ __launch_bounds__(256) void enc_kernel(
    const float* __restrict__ hT, const float* __restrict__ encW,
    const float* __restrict__ encB, const float* __restrict__ qW,
    const float* __restrict__ qB, const float* __restrict__ eps,
    const float* __restrict__ pm, const float* __restrict__ pls,
    float* __restrict__ z0, float* __restrict__ out)
{
  __shared__ float hTl[4][128];
  __shared__ float ctx[4][64];
  __shared__ float ql[4][64];
  const int t = threadIdx.x;
  const int b0 = blockIdx.x * 4;
  const int lb = t >> 6, j = t & 63;

  for (int i = t; i < 512; i += 256) hTl[i>>7][i&127] = hT[b0*H_ + i];
  __syncthreads();

  float acc = encB[j];
  #pragma unroll
  for (int k = 0; k < 128; k += 4) {
    f4 w = *(const f4*)&encW[j*128 + k];
    acc += hTl[lb][k]*w[0] + hTl[lb][k+1]*w[1] + hTl[lb][k+2]*w[2] + hTl[lb][k+3]*w[3];
  }
  ctx[lb][j] = acc;
  __syncthreads();

  float q = qB[j];
  #pragma unroll
  for (int k = 0; k < 64; k += 4) {
    f4 w = *(const f4*)&qW[j*64 + k];
    q += ctx[lb][k]*w[0] + ctx[lb][k+1]*w[1] + ctx[lb][k+2]*w[2] + ctx[lb][k+3]*w[3];
  }
  ql[lb][j] = q;
  __syncthreads();

  float kl = 0.f;
  if (j < 32) {
    float mean = ql[lb][j], ls = ql[lb][j+32];
    z0[(b0+lb)*Z_ + j] = mean + __expf(ls)*eps[(b0+lb)*Z_ + j];
    float pmj = pm[j], plsj = pls[j];
    float dm = mean - pmj;
    kl = plsj - ls + (__expf(2.f*ls) + dm*dm) / (2.f*__expf(2.f*plsj)) - 0.5f;
  }
  #pragma unroll
  for (int s2 = 32; s2 > 0; s2 >>= 1) kl += __shfl_down(kl, s2, 64);
  if (j == 0) atomicAdd(out + 1, kl * (1.f/1024.f));
}

// ---------------------------------------------------------------------------
// SDE: round-1 structure (1024 blocks x 1 row, 256 threads, weights in regs,
// launch_bounds(256,4) = 128 unified regs — exactly at demand) with
// CONFLICT-FREE LDS layouts:
//   h1 region  slots 0..15, interleaved slot = c*2+kh  (phase-2 kh halves are
//              16B apart -> adjacent banks; was 128B apart = 2-way conflict,
//              the bulk of the 3.4e7 conflict cycles)
//   gh region  slots 16..31, transposed slot = 16 + i*4 + kq (kq lanes span
//              16 consecutive banks)
//   h2 region  slots 36..51 (64B skew vs gh -> drift/diff lane groups hit
//              DISJOINT bank halves within each phase-3 ds_read_b128)
// ---------------------------------------------------------------------------
__global__ __launch_bounds__(256, 4) void sde_kernel(
    const float* __restrict__ z0, const float* __restrict__ ts,
    const float* __restrict__ dW, const float* __restrict__ xs,
    const float* __restrict__ fW1, const float* __restrict__ fb1,
    const float* __restrict__ fW2, const float* __restrict__ fb2,
    const float* __restrict__ fW3, const float* __restrict__ fb3,
    const float* __restrict__ gW1, const float* __restrict__ gb1,
    const float* __restrict__ gW2, const float* __restrict__ gb2,
    const float* __restrict__ pW, const float* __restrict__ pb,
    float* __restrict__ out)
{
  __shared__ h8 hAct[52];        // 0..15 h1 (interleaved), 16..31 gh (T), 36..51 h2 (T, skewed)
  __shared__ h8 zc[4];           // z f16 (32 values)
  __shared__ float tsL[516];

  const int t = threadIdx.x;
  const int b = blockIdx.x;

  // --- phase-1 role: row t of [fW1; gW1] ---
  const int row = t;
  const float* w1src = (row < 128) ? (fW1 + row*33) : (gW1 + (row-128)*33);
  const float twv = w1src[0];
  const float b1v = (row < 128) ? fb1[row] : gb1[row-128];
  h8 w1z[4];
  #pragma unroll
  for (int c = 0; c < 4; ++c) {       // stride-33 rows: scalar loads (startup only)
    h8 w;
    #pragma unroll
    for (int e = 0; e < 8; ++e) w[e] = (f16)w1src[1 + c*8 + e];
    w1z[c] = w;
  }
  // phase-1 destination slot (precomputed):
  //   row<128 : h1 chunk ch=row>>3        -> slot (ch&7)*2 + (ch>>3)
  //   row>=128: gh chunk ch=(row-128)>>3  -> slot 16 + (ch&3)*4 + (ch>>2)
  const int ch1 = (row < 128) ? (row >> 3) : ((row - 128) >> 3);
  const int sl1 = (row < 128) ? ((ch1 & 7)*2 + (ch1 >> 3))
                              : (16 + (ch1 & 3)*4 + (ch1 >> 2));
  // --- phase-2 role: out j2 = t>>1, k-half kh = t&1 ---
  const int j2 = t >> 1, kh = t & 1;
  const float b2v = fb2[j2];
  h8 w2[8];
  {
    const float* p2 = fW2 + j2*H_ + kh*64;
    #pragma unroll
    for (int c = 0; c < 8; ++c) w2[c] = ld8(p2 + c*8);
  }
  // phase-2 h2 destination slot: chunk ch2=j2>>3 -> 36 + (ch2&3)*4 + (ch2>>2)
  const int ch2 = j2 >> 3;
  const int sl2 = 36 + (ch2 & 3)*4 + (ch2 >> 2);
  // --- phase-3 role: zi = t>>3, sel (0 drift / 1 diff) = (t>>2)&1, kq = t&3 ---
  const int zi = t >> 3, sel = (t >> 2) & 1, kq = t & 3;
  h8 w3[4];
  {
    const float* p3 = sel ? (gW2 + zi*H_ + kq*32) : (fW3 + zi*H_ + kq*32);
    #pragma unroll
    for (int c = 0; c < 4; ++c) w3[c] = ld8(p3 + c*8);
  }
  const float b3v = sel ? gb2[zi] : fb3[zi];
  const bool zmaster = ((t & 7) == 0);
  const int rg3 = sel ? 16 : 36;           // diff reads gh, drift reads h2
  // --- proj role: d = t (t<64) ---
  h8 pw[4];
  float pbv = 0.f;
  if (t < 64) {
    const float* pp = pW + t*Z_;
    #pragma unroll
    for (int c = 0; c < 4; ++c) pw[c] = ld8(pp + c*8);
    pbv = pb[t];
  }

  for (int i = t; i < 515; i += 256) tsL[i] = ts[i];
  float zm = 0.f;                     // fp32 z master at (t&7)==0 lanes
  if (zmaster) {
    zm = z0[b*Z_ + zi];
    ((f16*)zc)[zi] = (f16)zm;
  }
  float loss = 0.f;
  __syncthreads();

  #pragma unroll 1
  for (int l = 0; l < NSTEP; ++l) {
    const float tl  = tsL[l];
    const float dt  = tsL[l+1] - tl;
    const float sdt = sqrtf(dt);
    const int ln = l + 1;
    const bool ev = ((ln & 1) == 0) && ln >= 2 && ln <= 512;
    const bool od = ((ln & 1) == 1) && ln >= 3 && ln <= 511;
    float dwv = 0.f;
    if (zmaster) dwv = dW[(l*B_ + b)*Z_ + zi];
    float xsv = 0.f;
    if (ev && t < 64) xsv = xs[(((ln-2)>>1)*B_ + b)*D_ + t];

    // phase 1: h1/gh = relu([t,z] @ W1.T + b), one row per thread
    {
      float a = fmaf(twv, tl, b1v);
      a = dot8(zc[0], w1z[0], a);
      a = dot8(zc[1], w1z[1], a);
      a = dot8(zc[2], w1z[2], a);
      a = dot8(zc[3], w1z[3], a);
      a = fmaxf(a, 0.f);
      ((f16*)hAct)[sl1*8 + (row & 7)] = (f16)a;
    }
    __syncthreads();   // A

    // phase 2: h2 = relu(h1 @ W2.T + b2), half-k + pair shfl
    // h1 chunk kh*8+c lives at slot c*2+kh: the two kh addresses are 16B
    // apart -> adjacent banks, conflict-free.
    {
      float c0 = 0.f, c1 = 0.f, c2 = 0.f, c3 = 0.f;
      c0 = dot8(hAct[ 0 + kh], w2[0], c0);
      c1 = dot8(hAct[ 2 + kh], w2[1], c1);
      c2 = dot8(hAct[ 4 + kh], w2[2], c2);
      c3 = dot8(hAct[ 6 + kh], w2[3], c3);
      c0 = dot8(hAct[ 8 + kh], w2[4], c0);
      c1 = dot8(hAct[10 + kh], w2[5], c1);
      c2 = dot8(hAct[12 + kh], w2[6], c2);
      c3 = dot8(hAct[14 + kh], w2[7], c3);
      float pp = (c0 + c1) + (c2 + c3);
      pp += __shfl_xor(pp, 1, 64);
      if (kh == 0) {
        float acc = fmaxf(pp + b2v, 0.f);
        ((f16*)hAct)[sl2*8 + (j2 & 7)] = (f16)acc;
      }
    }
    __syncthreads();   // B

    // phase 3: drift/diff quarter-k dots; transposed+skewed slots: per
    // instruction i the 8 lane-addresses (4 kq x 2 sel) span 32 distinct banks.
    {
      float c0 = 0.f, c1 = 0.f;
      c0 = dot8(hAct[rg3 +  0 + kq], w3[0], c0);
      c1 = dot8(hAct[rg3 +  4 + kq], w3[1], c1);
      c0 = dot8(hAct[rg3 +  8 + kq], w3[2], c0);
      c1 = dot8(hAct[rg3 + 12 + kq], w3[3], c1);
      float pp = c0 + c1;
      pp += __shfl_xor(pp, 1, 64);
      pp += __shfl_xor(pp, 2, 64);
      float acc = pp + b3v;                    // all 4 lanes of quartet agree
      float other = __shfl_xor(acc, 4, 64);    // drift lanes get diff, vice versa
      if (zmaster) {                           // sel==0 here: acc=drift, other=diff
        zm += acc*dt + other*(sdt*dwv);
        ((f16*)zc)[zi] = (f16)zm;
      }
    }
    __syncthreads();   // C

    // fused projection (wave 0) on needed steps
    if ((ev || od) && t < 64) {
      float c0 = 0.f, c1 = 0.f;
      c0 = dot8(zc[0], pw[0], c0);
      c1 = dot8(zc[1], pw[1], c1);
      c0 = dot8(zc[2], pw[2], c0);
      c1 = dot8(zc[3], pw[3], c1);
      float acc = pbv + c0 + c1;
      if (ev) { float d2 = acc - xsv; loss = fmaf(d2, d2, loss); }
      else out[2 + (((ln-3)>>1)*B_ + b)*D_ + t] = acc;
    }
  }

  if (t < 64) {
    #pragma unroll
    for (int s2 = 32; s2 > 0; s2 >>= 1) loss += __shfl_down(loss, s2, 64);
    if (t == 0) atomicAdd(out + 0, loss * (1.f/16777216.f));
  }
}

extern "C" void kernel_launch(void* const* d_in, const int* in_sizes, int n_in,
                              void* d_out, int out_size, void* d_ws, size_t ws_size,
                              hipStream_t stream) {
  (void)in_sizes; (void)n_in; (void)out_size; (void)ws_size;
  const float* xs   = (const float*)d_in[0];
  const float* ts   = (const float*)d_in[1];
  const float* eps  = (const float*)d_in[2];
  const float* dWp  = (const float*)d_in[3];
  const float* Wih  = (const float*)d_in[4];
  const float* Whh  = (const float*)d_in[5];
  const float* bih  = (const float*)d_in[6];
  const float* bhh  = (const float*)d_in[7];
  const float* encW = (const float*)d_in[8];
  const float* encB = (const float*)d_in[9];
  const float* qW   = (const float*)d_in[10];
  const float* qB   = (const float*)d_in[11];
  const float* fW1  = (const float*)d_in[12];
  const float* fb1  = (const float*)d_in[13];
  const float* fW2  = (const float*)d_in[14];
  const float* fb2  = (const float*)d_in[15];
  const float* fW3  = (const float*)d_in[16];
  const float* fb3  = (const float*)d_in[17];
  const float* gW1  = (const float*)d_in[18];
  const float* gb1  = (const float*)d_in[19];
  const float* gW2  = (const float*)d_in[20];
  const float* gb2  = (const float*)d_in[21];
  const float* pW   = (const float*)d_in[22];
  const float* pb   = (const float*)d_in[23];
  const float* pm   = (const float*)d_in[24];
  const float* pls  = (const float*)d_in[25];

  float* out = (float*)d_out;
  float* ws  = (float*)d_ws;
  float* hT = ws;              // 1024*128 floats
  float* z0 = ws + 131072;     // 1024*32 floats

  hipMemsetAsync(d_out, 0, 2*sizeof(float), stream);
  hipLaunchKernelGGL(gru_kernel, dim3(512), dim3(256), 0, stream,
                     xs, Wih, Whh, bih, bhh, hT);
  hipLaunchKernelGGL(enc_kernel, dim3(256), dim3(256), 0, stream,
                     hT, encW, encB, qW, qB, eps, pm, pls, z0, out);
  hipLaunchKernelGGL(sde_kernel, dim3(1024), dim3(256), 0, stream,
                     z0, ts, dWp, xs, fW1, fb1, fW2, fb2, fW3, fb3,
                     gW1, gb1, gW2, gb2, pW, pb, out);
}